// Round 1
// baseline (1443.127 us; speedup 1.0000x reference)
//
#include <hip/hip_runtime.h>

#define AS1 __attribute__((address_space(1)))
#define AS3 __attribute__((address_space(3)))

typedef __attribute__((ext_vector_type(8))) short short8;
typedef __attribute__((ext_vector_type(4))) float f32x4;
typedef __attribute__((ext_vector_type(4))) unsigned short u16x4;

__device__ __forceinline__ unsigned short f2bf(float f) {
  union { float f; unsigned u; } v; v.f = f;
  return (unsigned short)((v.u + 0x7fffu + ((v.u >> 16) & 1u)) >> 16);
}

__device__ __forceinline__ void gload_lds16(const void* g, void* l) {
  __builtin_amdgcn_global_load_lds((const AS1 unsigned*)g, (AS3 unsigned*)l, 16, 0, 0);
}

// ---------------------------------------------------------------------------
// Detect whether bool masks arrived as int32 (0/1 words) or as 1-byte bools.
// int32 path: every byte at (i % 4 != 0) is zero. u8 path: ~50% of them are 1.
__global__ void detect_fmt(const unsigned char* __restrict__ m, int* __restrict__ flag) {
  __shared__ int found;
  if (threadIdx.x == 0) found = 0;
  __syncthreads();
  for (int i = threadIdx.x; i < 4096; i += 256)
    if ((i & 3) != 0 && m[i] != 0) found = 1;
  __syncthreads();
  if (threadIdx.x == 0) flag[0] = found;
}

// ---------------------------------------------------------------------------
// Build W_eff = frozen ? codebook[idx] : (int8_mask ? alpha*int8 : w_float)
// Writes bf16 natural [R][C] and bf16 transposed [C][R] (LDS-tiled transpose).
__global__ __launch_bounds__(256) void build_w(
    const float* __restrict__ cb, const int* __restrict__ idx,
    const unsigned char* __restrict__ frozen8, const unsigned char* __restrict__ int8m8,
    const float* __restrict__ i8v, const float* __restrict__ wf,
    const float* __restrict__ alpha_p, const int* __restrict__ flag_p,
    unsigned short* __restrict__ w_nat, unsigned short* __restrict__ w_t,
    int R, int C) {
  __shared__ float tile[64][65];  // +1 pad: conflict-free transposed read
  const int t = threadIdx.x;
  const int tx = t & 63, ty = t >> 6;
  const int rBase = blockIdx.y * 64, cBase = blockIdx.x * 64;
  const float alpha = alpha_p[0];
  const int isU8 = flag_p[0];
  const int* frozen32 = (const int*)frozen8;
  const int* int8m32 = (const int*)int8m8;
#pragma unroll
  for (int i = 0; i < 16; ++i) {
    int r = i * 4 + ty;
    size_t off = (size_t)(rBase + r) * C + cBase + tx;
    int fz, im;
    if (isU8) { fz = frozen8[off]; im = int8m8[off]; }
    else      { fz = frozen32[off]; im = int8m32[off]; }
    float w;
    if (fz) w = cb[idx[off]];
    else if (im) w = alpha * i8v[off];
    else w = wf[off];
    w_nat[off] = f2bf(w);
    tile[r][tx] = w;
  }
  __syncthreads();
#pragma unroll
  for (int i = 0; i < 16; ++i) {
    int r = i * 4 + ty;  // row of transposed tile = original col
    size_t off = (size_t)(cBase + r) * R + rBase + tx;
    w_t[off] = f2bf(tile[tx][r]);
  }
}

// ---------------------------------------------------------------------------
__global__ __launch_bounds__(256) void cvt_bf16(const float* __restrict__ in,
                                                unsigned short* __restrict__ out, int n4) {
  int i = blockIdx.x * 256 + threadIdx.x;
  if (i < n4) {
    float4 v = ((const float4*)in)[i];
    u16x4 r;
    r.x = f2bf(v.x); r.y = f2bf(v.y); r.z = f2bf(v.z); r.w = f2bf(v.w);
    ((u16x4*)out)[i] = r;
  }
}

// ---------------------------------------------------------------------------
// B^T-layout bf16 GEMM: C[M][N] = A[M][K] * B[K][N] with B passed as Bt[N][K].
// 128x128 tile, BK=64, 4 waves (2x2), 16x16x32 MFMA, global_load_lds staging
// with pre-swizzled global source (XOR bits 4-6 by row&7) so swizzled
// ds_read_b128 fragment reads are ~conflict-free.
// MODE 0: out = bf16 c19(acc + bias)         (uses c_raw/rho_raw)
// MODE 1: outF = acc + bias, outB = bf16(same)
// MODE 2: outB = bf16(acc + bias)
// MODE 3: outF = acc + bias
template <int MODE>
__global__ __launch_bounds__(256) void gemm_bt(
    const unsigned short* __restrict__ A,   // [M][K] bf16
    const unsigned short* __restrict__ Bt,  // [N][K] bf16
    int M, int N, int K,
    const float* __restrict__ bias,
    const float* __restrict__ c_raw, const float* __restrict__ rho_raw,
    float* __restrict__ outF, unsigned short* __restrict__ outB) {
  __shared__ __align__(16) unsigned short ldsA[128 * 64];  // 16 KB
  __shared__ __align__(16) unsigned short ldsB[128 * 64];  // 16 KB
  const int t = threadIdx.x;
  const int l = t & 63, w = t >> 6;
  const int wr = w >> 1, wc = w & 1;
  const int lr = l & 15, q = l >> 4;
  const int tileM = blockIdx.y * 128, tileN = blockIdx.x * 128;

  f32x4 acc[4][4];
#pragma unroll
  for (int mi = 0; mi < 4; ++mi)
#pragma unroll
    for (int ni = 0; ni < 4; ++ni) acc[mi][ni] = (f32x4){0.f, 0.f, 0.f, 0.f};

  // Per-lane staging sources (hoisted; advance by kt each K-tile).
  const int chRow = l >> 3;   // row within 1KB chunk (8 rows of 128B)
  const int subSlot = l & 7;  // 16B slot within row
  const unsigned short* pa[4];
  const unsigned short* pb[4];
  unsigned short* la[4];
  unsigned short* lb[4];
#pragma unroll
  for (int i = 0; i < 4; ++i) {
    int chunk = 4 * w + i;
    int row = chunk * 8 + chRow;        // 0..127
    int sl = subSlot ^ (row & 7);       // inverse swizzle on SOURCE
    pa[i] = A + (size_t)(tileM + row) * K + sl * 8;
    pb[i] = Bt + (size_t)(tileN + row) * K + sl * 8;
    la[i] = ldsA + chunk * 512;         // linear dest, 1KB/wave-instr
    lb[i] = ldsB + chunk * 512;
  }
  // Fragment read byte offsets (thread-constant, swizzled).
  int offA[2][4], offB[2][4];
#pragma unroll
  for (int kk = 0; kk < 2; ++kk)
#pragma unroll
    for (int i = 0; i < 4; ++i) {
      int rowA = wr * 64 + i * 16 + lr;
      offA[kk][i] = (rowA * 128 + kk * 64 + q * 16) ^ ((rowA & 7) << 4);
      int rowB = wc * 64 + i * 16 + lr;
      offB[kk][i] = (rowB * 128 + kk * 64 + q * 16) ^ ((rowB & 7) << 4);
    }

  for (int kt = 0; kt < K; kt += 64) {
#pragma unroll
    for (int i = 0; i < 4; ++i) gload_lds16(pa[i] + kt, la[i]);
#pragma unroll
    for (int i = 0; i < 4; ++i) gload_lds16(pb[i] + kt, lb[i]);
    __syncthreads();  // compiler emits vmcnt(0) drain before barrier
#pragma unroll
    for (int kk = 0; kk < 2; ++kk) {
      short8 af[4], bf[4];
#pragma unroll
      for (int mi = 0; mi < 4; ++mi)
        af[mi] = *(const short8*)((const char*)ldsA + offA[kk][mi]);
#pragma unroll
      for (int ni = 0; ni < 4; ++ni)
        bf[ni] = *(const short8*)((const char*)ldsB + offB[kk][ni]);
#pragma unroll
      for (int mi = 0; mi < 4; ++mi)
#pragma unroll
        for (int ni = 0; ni < 4; ++ni)
          acc[mi][ni] = __builtin_amdgcn_mfma_f32_16x16x32_bf16(af[mi], bf[ni], acc[mi][ni], 0, 0, 0);
    }
    __syncthreads();  // protect LDS before next stage
  }

  // Epilogue. C/D layout: col = lane&15, row = (lane>>4)*4 + reg  [m89/m91]
#pragma unroll
  for (int ni = 0; ni < 4; ++ni) {
    int col = tileN + wc * 64 + ni * 16 + lr;
    float bv = bias[col];
    float cc = 0.f, rr = 0.f, L = 0.f;
    if constexpr (MODE == 0) {
      cc = fmaxf(c_raw[col], 0.1f);
      rr = fmaxf(rho_raw[col], 0.0f);
      L = 6.0f * cc;
    }
#pragma unroll
    for (int mi = 0; mi < 4; ++mi) {
      int row0 = tileM + wr * 64 + mi * 16 + q * 4;
#pragma unroll
      for (int j = 0; j < 4; ++j) {
        float v = acc[mi][ni][j] + bv;
        size_t off = (size_t)(row0 + j) * N + col;
        if constexpr (MODE == 0) {
          float scaled = v / cc;
          float fn = floorf(scaled);
          float tt = scaled - fn;
          float h = tt * (1.0f - tt);
          int ip = (int)fn;
          float sgn = (ip & 1) ? -1.0f : 1.0f;
          float interior = cc * (sgn * h + rr * h * h);
          float res = (v >= L) ? (v - L) : ((v <= -L) ? (v + L) : interior);
          outB[off] = f2bf(res);
        } else if constexpr (MODE == 1) {
          outF[off] = v;
          outB[off] = f2bf(v);
        } else if constexpr (MODE == 2) {
          outB[off] = f2bf(v);
        } else {
          outF[off] = v;
        }
      }
    }
  }
}

// ---------------------------------------------------------------------------
extern "C" void kernel_launch(void* const* d_in, const int* in_sizes, int n_in,
                              void* d_out, int out_size, void* d_ws, size_t ws_size,
                              hipStream_t stream) {
  (void)in_sizes; (void)n_in; (void)out_size; (void)ws_size;
  const float* x = (const float*)d_in[0];
  const float* cb1 = (const float*)d_in[1];
  const float* cb2 = (const float*)d_in[2];
  const int* idx1 = (const int*)d_in[3];
  const int* idx2 = (const int*)d_in[4];
  const unsigned char* fz1 = (const unsigned char*)d_in[5];
  const unsigned char* fz2 = (const unsigned char*)d_in[6];
  const unsigned char* im1 = (const unsigned char*)d_in[7];
  const unsigned char* im2 = (const unsigned char*)d_in[8];
  const float* i8v1 = (const float*)d_in[9];
  const float* i8v2 = (const float*)d_in[10];
  const float* wf1 = (const float*)d_in[11];
  const float* wf2 = (const float*)d_in[12];
  const float* a1 = (const float*)d_in[13];
  const float* a2 = (const float*)d_in[14];
  const float* b1 = (const float*)d_in[15];
  const float* b2 = (const float*)d_in[16];
  const float* db1 = (const float*)d_in[17];
  const float* db2 = (const float*)d_in[18];
  const float* c_raw = (const float*)d_in[19];
  const float* rho_raw = (const float*)d_in[20];

  // Workspace layout (bytes)
  char* ws = (char*)d_ws;
  const size_t WSZ = 33554432;  // 2048*8192*2B
  unsigned short* W1T = (unsigned short*)(ws + 0 * WSZ);            // [8192][2048] = W1[k][n] as Bt
  unsigned short* W1N = (unsigned short*)(ws + 1 * WSZ);            // [2048][8192]
  unsigned short* W2T = (unsigned short*)(ws + 2 * WSZ);            // [2048][8192]
  unsigned short* W2N = (unsigned short*)(ws + 3 * WSZ);            // [8192][2048]
  unsigned short* XB = (unsigned short*)(ws + 4 * WSZ);             // [4096][2048] bf16 x
  unsigned short* H = (unsigned short*)(ws + 4 * WSZ + 16777216);   // [4096][8192] h, then y
  unsigned short* ZB = (unsigned short*)(ws + 4 * WSZ + 16777216 + 67108864);  // [4096][2048]
  int* flag = (int*)(ws + 4 * WSZ + 16777216 + 67108864 + 16777216);
  float* dec = (float*)d_out;              // output 0: [4096][2048]
  float* zf = (float*)d_out + 8388608;     // output 1: [4096][2048]

  detect_fmt<<<1, 256, 0, stream>>>(fz1, flag);
  // W1: R=2048 (IN_DIM), C=8192 (H)
  build_w<<<dim3(8192 / 64, 2048 / 64), 256, 0, stream>>>(cb1, idx1, fz1, im1, i8v1, wf1, a1, flag, W1N, W1T, 2048, 8192);
  // W2: R=8192, C=2048
  build_w<<<dim3(2048 / 64, 8192 / 64), 256, 0, stream>>>(cb2, idx2, fz2, im2, i8v2, wf2, a2, flag, W2N, W2T, 8192, 2048);
  cvt_bf16<<<8192, 256, 0, stream>>>(x, XB, 2097152);

  // G1: h = c19(x @ W1 + b1)          [4096 x 8192], B[k][n]=W1[k][n] -> Bt = W1T
  gemm_bt<0><<<dim3(64, 32), 256, 0, stream>>>(XB, W1T, 4096, 8192, 2048, b1, c_raw, rho_raw, nullptr, H);
  // G2: z = h @ W2 + b2               [4096 x 2048], Bt = W2T
  gemm_bt<1><<<dim3(16, 32), 256, 0, stream>>>(H, W2T, 4096, 2048, 8192, b2, nullptr, nullptr, zf, ZB);
  // G3: y = z @ W2^T + db1            [4096 x 8192], B[k][n]=W2[n][k] -> Bt = W2 natural
  gemm_bt<2><<<dim3(64, 32), 256, 0, stream>>>(ZB, W2N, 4096, 8192, 2048, db1, nullptr, nullptr, nullptr, H);
  // G4: dec = y @ W1^T + db2          [4096 x 2048], Bt = W1 natural
  gemm_bt<3><<<dim3(16, 32), 256, 0, stream>>>(H, W1N, 4096, 2048, 8192, db2, nullptr, nullptr, dec, nullptr);
}

// Round 2
// 1301.883 us; speedup vs baseline: 1.1085x; 1.1085x over previous
//
#include <hip/hip_runtime.h>

#define AS1 __attribute__((address_space(1)))
#define AS3 __attribute__((address_space(3)))

typedef __attribute__((ext_vector_type(8))) short short8;
typedef __attribute__((ext_vector_type(8))) float float8;
typedef __attribute__((ext_vector_type(8))) int int8v;
typedef __attribute__((ext_vector_type(4))) float f32x4;
typedef __attribute__((ext_vector_type(4))) unsigned short u16x4;

__device__ __forceinline__ unsigned short f2bf(float f) {
  union { float f; unsigned u; } v; v.f = f;
  return (unsigned short)((v.u + 0x7fffu + ((v.u >> 16) & 1u)) >> 16);
}

__device__ __forceinline__ void gload_lds16(const void* g, void* l) {
  __builtin_amdgcn_global_load_lds((const AS1 unsigned*)g, (AS3 unsigned*)l, 16, 0, 0);
}

#define MEMFENCE asm volatile("" ::: "memory")
#define BARRIER() do { MEMFENCE; __builtin_amdgcn_s_barrier(); MEMFENCE; } while (0)

// ---------------------------------------------------------------------------
__global__ void detect_fmt(const unsigned char* __restrict__ m, int* __restrict__ flag) {
  __shared__ int found;
  if (threadIdx.x == 0) found = 0;
  __syncthreads();
  for (int i = threadIdx.x; i < 4096; i += 256)
    if ((i & 3) != 0 && m[i] != 0) found = 1;
  __syncthreads();
  if (threadIdx.x == 0) flag[0] = found;
}

// ---------------------------------------------------------------------------
// Vectorized weight build: 8 elems/thread/pass, 32B value loads, codebook in
// LDS, short8 stores; padded LDS tile transpose (2-way aliasing = free).
__global__ __launch_bounds__(256) void build_w2(
    const float* __restrict__ cb, const int* __restrict__ idx,
    const unsigned char* __restrict__ fz8, const unsigned char* __restrict__ im8,
    const float* __restrict__ i8v, const float* __restrict__ wf,
    const float* __restrict__ alpha_p, const int* __restrict__ flag_p,
    unsigned short* __restrict__ w_nat, unsigned short* __restrict__ w_t,
    int R, int C) {
  __shared__ float cbs[256];
  __shared__ float tile[64][65];
  const int t = threadIdx.x;
  cbs[t] = cb[t];
  const int rBase = blockIdx.y * 64, cBase = blockIdx.x * 64;
  const float alpha = alpha_p[0];
  const int isU8 = flag_p[0];
  __syncthreads();
#pragma unroll
  for (int p = 0; p < 2; ++p) {
    const int rl = p * 32 + (t >> 3);
    const int cl = (t & 7) * 8;
    const size_t off = (size_t)(rBase + rl) * C + cBase + cl;
    float8 wv = *(const float8*)(wf + off);
    float8 qv = *(const float8*)(i8v + off);
    int8v iv = *(const int8v*)(idx + off);
    unsigned fzm[8], imm[8];
    if (isU8) {
      unsigned long long fm = *(const unsigned long long*)(fz8 + off);
      unsigned long long im = *(const unsigned long long*)(im8 + off);
#pragma unroll
      for (int k = 0; k < 8; ++k) { fzm[k] = (fm >> (8 * k)) & 255ull; imm[k] = (im >> (8 * k)) & 255ull; }
    } else {
      int8v fv = *(const int8v*)((const int*)fz8 + off);
      int8v mv = *(const int8v*)((const int*)im8 + off);
#pragma unroll
      for (int k = 0; k < 8; ++k) { fzm[k] = fv[k]; imm[k] = mv[k]; }
    }
    short8 o;
#pragma unroll
    for (int k = 0; k < 8; ++k) {
      float r = fzm[k] ? cbs[iv[k] & 255] : (imm[k] ? alpha * qv[k] : wv[k]);
      o[k] = (short)f2bf(r);
      tile[rl][cl + k] = r;
    }
    *(short8*)(w_nat + off) = o;
  }
  __syncthreads();
#pragma unroll
  for (int p = 0; p < 2; ++p) {
    const int cl = p * 32 + (t >> 3);
    const int r0 = (t & 7) * 8;
    short8 o;
#pragma unroll
    for (int j = 0; j < 8; ++j) o[j] = (short)f2bf(tile[r0 + j][cl]);
    *(short8*)(w_t + (size_t)(cBase + cl) * R + rBase + r0) = o;
  }
}

// ---------------------------------------------------------------------------
__global__ __launch_bounds__(256) void cvt_bf16(const float* __restrict__ in,
                                                unsigned short* __restrict__ out, int n4) {
  int i = blockIdx.x * 256 + threadIdx.x;
  if (i < n4) {
    float4 v = ((const float4*)in)[i];
    u16x4 r;
    r.x = f2bf(v.x); r.y = f2bf(v.y); r.z = f2bf(v.z); r.w = f2bf(v.w);
    ((u16x4*)out)[i] = r;
  }
}

// ---------------------------------------------------------------------------
// 256x256 8-phase bf16 GEMM (T1+T2+T3+T4+T5). C = A[M][K] * B, B given as
// Bt[N][K]. 512 thr = 8 waves (2M x 4N), BK=64, 128KB LDS: 2buf x 4 halves
// (Ah0,Ah1,Bh0,Bh1) of [128][64] bf16, XOR-swizzled via pre-swizzled global
// source (verified R1: 0 bank conflicts).
// Stagger: K-tile t stages {P1:Ah0(t+1), P2:Ah1(t+1), P3:Bh0(t+2), P4:Bh1(t+2)},
// one counted vmcnt(4) per K-tile. At each boundary the retired 4 ops are
// exactly tile t+1's halves; in-flight 4 = tile t+2's B halves.
// MODE 0: outB = bf16 c19(acc+bias);  MODE 2: outB = bf16(acc+bias)
template <int MODE>
__global__ __launch_bounds__(512, 2) void gemm8(
    const unsigned short* __restrict__ A, const unsigned short* __restrict__ Bt,
    int M, int N, int K,
    const float* __restrict__ bias,
    const float* __restrict__ c_raw, const float* __restrict__ rho_raw,
    unsigned short* __restrict__ outB) {
  extern __shared__ unsigned short lds8[];  // 131072 B = 2 buf x 4 halves x 16KB
  const int t = threadIdx.x;
  const int l = t & 63, w = t >> 6;
  const int wm = w >> 2, wn = w & 3;
  const int lr = l & 15, q = l >> 4;

  // XCD-aware swizzle (nwg % 8 == 0 for our grids)
  const int nwg = gridDim.x;
  const int id = (blockIdx.x & 7) * (nwg >> 3) + (blockIdx.x >> 3);
  const int nbx = N >> 8;
  const int tileM = (id / nbx) * 256, tileN = (id % nbx) * 256;

  f32x4 acc[8][4];
#pragma unroll
  for (int mi = 0; mi < 8; ++mi)
#pragma unroll
    for (int ni = 0; ni < 4; ++ni) acc[mi][ni] = (f32x4){0.f, 0.f, 0.f, 0.f};

  // Staging addresses: wave w instr i covers half-local rows w*16+i*8 .. +7.
  const int srow = l >> 3, sslot = l & 7;
  const unsigned short* aSrc[2];
  const unsigned short* bSrc[2];
  int ldsOff[2];
#pragma unroll
  for (int i = 0; i < 2; ++i) {
    int rl = w * 16 + i * 8 + srow;
    int sl = sslot ^ (rl & 7);  // inverse swizzle on SOURCE
    aSrc[i] = A + (size_t)(tileM + rl) * K + sl * 8;
    bSrc[i] = Bt + (size_t)(tileN + rl) * K + sl * 8;
    ldsOff[i] = (w * 2 + i) * 512;  // shorts
  }
  const size_t dK = (size_t)128 * K;  // half1 source delta (elements)

#define STAGE_A0(buf, kt) { gload_lds16(aSrc[0] + (kt), lds8 + (buf)*32768 + 0*8192 + ldsOff[0]); \
                            gload_lds16(aSrc[1] + (kt), lds8 + (buf)*32768 + 0*8192 + ldsOff[1]); }
#define STAGE_A1(buf, kt) { gload_lds16(aSrc[0] + dK + (kt), lds8 + (buf)*32768 + 1*8192 + ldsOff[0]); \
                            gload_lds16(aSrc[1] + dK + (kt), lds8 + (buf)*32768 + 1*8192 + ldsOff[1]); }
#define STAGE_B0(buf, kt) { gload_lds16(bSrc[0] + (kt), lds8 + (buf)*32768 + 2*8192 + ldsOff[0]); \
                            gload_lds16(bSrc[1] + (kt), lds8 + (buf)*32768 + 2*8192 + ldsOff[1]); }
#define STAGE_B1(buf, kt) { gload_lds16(bSrc[0] + dK + (kt), lds8 + (buf)*32768 + 3*8192 + ldsOff[0]); \
                            gload_lds16(bSrc[1] + dK + (kt), lds8 + (buf)*32768 + 3*8192 + ldsOff[1]); }

  // Fragment read offsets: byte = row*128 + ((kk*64 + q*16) ^ ((lr&7)<<4)),
  // row&7 == lr&7 cancels the store-side swizzle (verified R1).
  const int sw = (lr & 7) << 4;
  const int k0 = (q * 16) ^ sw;
  const int k1 = (64 + q * 16) ^ sw;
  const char* ldsc = (const char*)lds8;
  const int bRowBase = (wn & 1) * 64;

  const int nt = K >> 6;
  // Prologue: tile0 all 4 halves -> buf0; tile1 B halves -> buf1.
  STAGE_A0(0, 0); STAGE_A1(0, 0); STAGE_B0(0, 0); STAGE_B1(0, 0);
  {
    int kt1 = (nt > 1) ? 64 : 0;
    STAGE_B0(1, kt1); STAGE_B1(1, kt1);
  }
  asm volatile("s_waitcnt vmcnt(4)" ::: "memory");
  BARRIER();

  short8 af[4][2], bf[4][2];
  for (int tt = 0; tt < nt; ++tt) {
    const int cur = tt & 1, nx = cur ^ 1;
    const int ktA = (tt + 1 < nt ? tt + 1 : 0) << 6;
    const int ktB = (tt + 2 < nt ? tt + 2 : 0) << 6;
    const int aB = cur * 65536 + wm * 16384;                  // bytes
    const int bB = cur * 65536 + 32768 + (wn >> 1) * 16384;   // bytes

    // ---- P1: read A(mi0-3), B(ni0-1); stage Ah0(t+1); MFMA q(0,0)
#pragma unroll
    for (int mi = 0; mi < 4; ++mi) {
      af[mi][0] = *(const short8*)(ldsc + aB + (mi * 16 + lr) * 128 + k0);
      af[mi][1] = *(const short8*)(ldsc + aB + (mi * 16 + lr) * 128 + k1);
    }
#pragma unroll
    for (int ni = 0; ni < 2; ++ni) {
      bf[ni][0] = *(const short8*)(ldsc + bB + (bRowBase + ni * 16 + lr) * 128 + k0);
      bf[ni][1] = *(const short8*)(ldsc + bB + (bRowBase + ni * 16 + lr) * 128 + k1);
    }
    STAGE_A0(nx, ktA);
    BARRIER();
    asm volatile("s_waitcnt lgkmcnt(0)" ::: "memory");
    __builtin_amdgcn_s_setprio(1);
#pragma unroll
    for (int mi = 0; mi < 4; ++mi)
#pragma unroll
      for (int ni = 0; ni < 2; ++ni) {
        acc[mi][ni] = __builtin_amdgcn_mfma_f32_16x16x32_bf16(af[mi][0], bf[ni][0], acc[mi][ni], 0, 0, 0);
        acc[mi][ni] = __builtin_amdgcn_mfma_f32_16x16x32_bf16(af[mi][1], bf[ni][1], acc[mi][ni], 0, 0, 0);
      }
    __builtin_amdgcn_s_setprio(0);
    BARRIER();

    // ---- P2: read B(ni2-3); stage Ah1(t+1); MFMA q(0,1)
#pragma unroll
    for (int ni = 2; ni < 4; ++ni) {
      bf[ni][0] = *(const short8*)(ldsc + bB + (bRowBase + ni * 16 + lr) * 128 + k0);
      bf[ni][1] = *(const short8*)(ldsc + bB + (bRowBase + ni * 16 + lr) * 128 + k1);
    }
    STAGE_A1(nx, ktA);
    BARRIER();
    asm volatile("s_waitcnt lgkmcnt(0)" ::: "memory");
    __builtin_amdgcn_s_setprio(1);
#pragma unroll
    for (int mi = 0; mi < 4; ++mi)
#pragma unroll
      for (int ni = 2; ni < 4; ++ni) {
        acc[mi][ni] = __builtin_amdgcn_mfma_f32_16x16x32_bf16(af[mi][0], bf[ni][0], acc[mi][ni], 0, 0, 0);
        acc[mi][ni] = __builtin_amdgcn_mfma_f32_16x16x32_bf16(af[mi][1], bf[ni][1], acc[mi][ni], 0, 0, 0);
      }
    __builtin_amdgcn_s_setprio(0);
    BARRIER();

    // ---- P3: read A(mi4-7); stage Bh0(t+2) into buf[cur] (B reads done at P2); MFMA q(1,1)
#pragma unroll
    for (int mi = 0; mi < 4; ++mi) {
      af[mi][0] = *(const short8*)(ldsc + aB + ((mi + 4) * 16 + lr) * 128 + k0);
      af[mi][1] = *(const short8*)(ldsc + aB + ((mi + 4) * 16 + lr) * 128 + k1);
    }
    STAGE_B0(cur, ktB);
    BARRIER();
    asm volatile("s_waitcnt lgkmcnt(0)" ::: "memory");
    __builtin_amdgcn_s_setprio(1);
#pragma unroll
    for (int mi = 0; mi < 4; ++mi)
#pragma unroll
      for (int ni = 2; ni < 4; ++ni) {
        acc[mi + 4][ni] = __builtin_amdgcn_mfma_f32_16x16x32_bf16(af[mi][0], bf[ni][0], acc[mi + 4][ni], 0, 0, 0);
        acc[mi + 4][ni] = __builtin_amdgcn_mfma_f32_16x16x32_bf16(af[mi][1], bf[ni][1], acc[mi + 4][ni], 0, 0, 0);
      }
    __builtin_amdgcn_s_setprio(0);
    BARRIER();

    // ---- P4: (regs reused) stage Bh1(t+2); MFMA q(1,0); counted vmcnt
    STAGE_B1(cur, ktB);
    BARRIER();
    __builtin_amdgcn_s_setprio(1);
#pragma unroll
    for (int mi = 0; mi < 4; ++mi)
#pragma unroll
      for (int ni = 0; ni < 2; ++ni) {
        acc[mi + 4][ni] = __builtin_amdgcn_mfma_f32_16x16x32_bf16(af[mi][0], bf[ni][0], acc[mi + 4][ni], 0, 0, 0);
        acc[mi + 4][ni] = __builtin_amdgcn_mfma_f32_16x16x32_bf16(af[mi][1], bf[ni][1], acc[mi + 4][ni], 0, 0, 0);
      }
    __builtin_amdgcn_s_setprio(0);
    asm volatile("s_waitcnt vmcnt(4)" ::: "memory");
    BARRIER();
  }
#undef STAGE_A0
#undef STAGE_A1
#undef STAGE_B0
#undef STAGE_B1

  // Epilogue. C/D layout: col = lr (B index), row = q*4 + j (verified R1).
#pragma unroll
  for (int ni = 0; ni < 4; ++ni) {
    const int col = tileN + wn * 64 + ni * 16 + lr;
    const float bv = bias[col];
    float cc = 0.f, rr = 0.f, L = 0.f;
    if constexpr (MODE == 0) {
      cc = fmaxf(c_raw[col], 0.1f);
      rr = fmaxf(rho_raw[col], 0.0f);
      L = 6.0f * cc;
    }
#pragma unroll
    for (int mi = 0; mi < 8; ++mi) {
      const int row0 = tileM + wm * 128 + mi * 16 + q * 4;
#pragma unroll
      for (int j = 0; j < 4; ++j) {
        float v = acc[mi][ni][j] + bv;
        size_t off = (size_t)(row0 + j) * N + col;
        if constexpr (MODE == 0) {
          float scaled = v / cc;
          float fn = floorf(scaled);
          float ttf = scaled - fn;
          float h = ttf * (1.0f - ttf);
          int ip = (int)fn;
          float sgn = (ip & 1) ? -1.0f : 1.0f;
          float interior = cc * (sgn * h + rr * h * h);
          float res = (v >= L) ? (v - L) : ((v <= -L) ? (v + L) : interior);
          outB[off] = f2bf(res);
        } else {
          outB[off] = f2bf(v);
        }
      }
    }
  }
}

// ---------------------------------------------------------------------------
// R1-verified 128x128 2-barrier GEMM, kept for G2/G4 (N=2048: only 128 tiles
// at 256^2 -> half-idle GPU; split-K is the next-round candidate).
// MODE 1: outF = acc+bias, outB = bf16(same);  MODE 3: outF = acc+bias
template <int MODE>
__global__ __launch_bounds__(256) void gemm_bt(
    const unsigned short* __restrict__ A, const unsigned short* __restrict__ Bt,
    int M, int N, int K,
    const float* __restrict__ bias,
    float* __restrict__ outF, unsigned short* __restrict__ outB) {
  __shared__ __align__(16) unsigned short ldsA[128 * 64];
  __shared__ __align__(16) unsigned short ldsB[128 * 64];
  const int t = threadIdx.x;
  const int l = t & 63, w = t >> 6;
  const int wr = w >> 1, wc = w & 1;
  const int lr = l & 15, q = l >> 4;
  const int tileM = blockIdx.y * 128, tileN = blockIdx.x * 128;

  f32x4 acc[4][4];
#pragma unroll
  for (int mi = 0; mi < 4; ++mi)
#pragma unroll
    for (int ni = 0; ni < 4; ++ni) acc[mi][ni] = (f32x4){0.f, 0.f, 0.f, 0.f};

  const int chRow = l >> 3;
  const int subSlot = l & 7;
  const unsigned short* pa[4];
  const unsigned short* pb[4];
  unsigned short* la[4];
  unsigned short* lb[4];
#pragma unroll
  for (int i = 0; i < 4; ++i) {
    int chunk = 4 * w + i;
    int row = chunk * 8 + chRow;
    int sl = subSlot ^ (row & 7);
    pa[i] = A + (size_t)(tileM + row) * K + sl * 8;
    pb[i] = Bt + (size_t)(tileN + row) * K + sl * 8;
    la[i] = ldsA + chunk * 512;
    lb[i] = ldsB + chunk * 512;
  }
  int offA[2][4], offB[2][4];
#pragma unroll
  for (int kk = 0; kk < 2; ++kk)
#pragma unroll
    for (int i = 0; i < 4; ++i) {
      int rowA = wr * 64 + i * 16 + lr;
      offA[kk][i] = (rowA * 128 + kk * 64 + q * 16) ^ ((rowA & 7) << 4);
      int rowB = wc * 64 + i * 16 + lr;
      offB[kk][i] = (rowB * 128 + kk * 64 + q * 16) ^ ((rowB & 7) << 4);
    }

  for (int kt = 0; kt < K; kt += 64) {
#pragma unroll
    for (int i = 0; i < 4; ++i) gload_lds16(pa[i] + kt, la[i]);
#pragma unroll
    for (int i = 0; i < 4; ++i) gload_lds16(pb[i] + kt, lb[i]);
    __syncthreads();
#pragma unroll
    for (int kk = 0; kk < 2; ++kk) {
      short8 af[4], bfr[4];
#pragma unroll
      for (int mi = 0; mi < 4; ++mi)
        af[mi] = *(const short8*)((const char*)ldsA + offA[kk][mi]);
#pragma unroll
      for (int ni = 0; ni < 4; ++ni)
        bfr[ni] = *(const short8*)((const char*)ldsB + offB[kk][ni]);
#pragma unroll
      for (int mi = 0; mi < 4; ++mi)
#pragma unroll
        for (int ni = 0; ni < 4; ++ni)
          acc[mi][ni] = __builtin_amdgcn_mfma_f32_16x16x32_bf16(af[mi], bfr[ni], acc[mi][ni], 0, 0, 0);
    }
    __syncthreads();
  }

#pragma unroll
  for (int ni = 0; ni < 4; ++ni) {
    int col = tileN + wc * 64 + ni * 16 + lr;
    float bv = bias[col];
#pragma unroll
    for (int mi = 0; mi < 4; ++mi) {
      int row0 = tileM + wr * 64 + mi * 16 + q * 4;
#pragma unroll
      for (int j = 0; j < 4; ++j) {
        float v = acc[mi][ni][j] + bv;
        size_t off = (size_t)(row0 + j) * N + col;
        if constexpr (MODE == 1) {
          outF[off] = v;
          outB[off] = f2bf(v);
        } else {
          outF[off] = v;
        }
      }
    }
  }
}

// ---------------------------------------------------------------------------
extern "C" void kernel_launch(void* const* d_in, const int* in_sizes, int n_in,
                              void* d_out, int out_size, void* d_ws, size_t ws_size,
                              hipStream_t stream) {
  (void)in_sizes; (void)n_in; (void)out_size; (void)ws_size;
  const float* x = (const float*)d_in[0];
  const float* cb1 = (const float*)d_in[1];
  const float* cb2 = (const float*)d_in[2];
  const int* idx1 = (const int*)d_in[3];
  const int* idx2 = (const int*)d_in[4];
  const unsigned char* fz1 = (const unsigned char*)d_in[5];
  const unsigned char* fz2 = (const unsigned char*)d_in[6];
  const unsigned char* im1 = (const unsigned char*)d_in[7];
  const unsigned char* im2 = (const unsigned char*)d_in[8];
  const float* i8v1 = (const float*)d_in[9];
  const float* i8v2 = (const float*)d_in[10];
  const float* wf1 = (const float*)d_in[11];
  const float* wf2 = (const float*)d_in[12];
  const float* a1 = (const float*)d_in[13];
  const float* a2 = (const float*)d_in[14];
  const float* b1 = (const float*)d_in[15];
  const float* b2 = (const float*)d_in[16];
  const float* db1 = (const float*)d_in[17];
  const float* db2 = (const float*)d_in[18];
  const float* c_raw = (const float*)d_in[19];
  const float* rho_raw = (const float*)d_in[20];

  char* ws = (char*)d_ws;
  const size_t WSZ = 33554432;  // 2048*8192*2B
  unsigned short* W1T = (unsigned short*)(ws + 0 * WSZ);            // [8192][2048]
  unsigned short* W1N = (unsigned short*)(ws + 1 * WSZ);            // [2048][8192]
  unsigned short* W2T = (unsigned short*)(ws + 2 * WSZ);            // [2048][8192]
  unsigned short* W2N = (unsigned short*)(ws + 3 * WSZ);            // [8192][2048]
  unsigned short* XB = (unsigned short*)(ws + 4 * WSZ);             // [4096][2048]
  unsigned short* H = (unsigned short*)(ws + 4 * WSZ + 16777216);   // [4096][8192]
  unsigned short* ZB = (unsigned short*)(ws + 4 * WSZ + 16777216 + 67108864);  // [4096][2048]
  int* flag = (int*)(ws + 4 * WSZ + 16777216 + 67108864 + 16777216);
  float* dec = (float*)d_out;
  float* zf = (float*)d_out + 8388608;

  // 128 KB dynamic LDS opt-in for the 8-phase kernels.
  (void)hipFuncSetAttribute((const void*)gemm8<0>, hipFuncAttributeMaxDynamicSharedMemorySize, 131072);
  (void)hipFuncSetAttribute((const void*)gemm8<2>, hipFuncAttributeMaxDynamicSharedMemorySize, 131072);

  detect_fmt<<<1, 256, 0, stream>>>(fz1, flag);
  build_w2<<<dim3(8192 / 64, 2048 / 64), 256, 0, stream>>>(cb1, idx1, fz1, im1, i8v1, wf1, a1, flag, W1N, W1T, 2048, 8192);
  build_w2<<<dim3(2048 / 64, 8192 / 64), 256, 0, stream>>>(cb2, idx2, fz2, im2, i8v2, wf2, a2, flag, W2N, W2T, 8192, 2048);
  cvt_bf16<<<8192, 256, 0, stream>>>(x, XB, 2097152);

  // G1: h = c19(x @ W1 + b1)   [4096 x 8192 x K2048], 8-phase
  gemm8<0><<<512, 512, 131072, stream>>>(XB, W1T, 4096, 8192, 2048, b1, c_raw, rho_raw, H);
  // G2: z = h @ W2 + b2        [4096 x 2048 x K8192], R1 kernel
  gemm_bt<1><<<dim3(16, 32), 256, 0, stream>>>(H, W2T, 4096, 2048, 8192, b2, zf, ZB);
  // G3: y = z @ W2^T + db1     [4096 x 8192 x K2048], 8-phase
  gemm8<2><<<512, 512, 131072, stream>>>(ZB, W2N, 4096, 8192, 2048, db1, nullptr, nullptr, H);
  // G4: dec = y @ W1^T + db2   [4096 x 2048 x K8192], R1 kernel
  gemm_bt<3><<<dim3(16, 32), 256, 0, stream>>>(H, W1N, 4096, 2048, 8192, db2, dec, nullptr);
}

// Round 3
// 1182.897 us; speedup vs baseline: 1.2200x; 1.1006x over previous
//
#include <hip/hip_runtime.h>

#define AS1 __attribute__((address_space(1)))
#define AS3 __attribute__((address_space(3)))

typedef __attribute__((ext_vector_type(8))) short short8;
typedef __attribute__((ext_vector_type(8))) float float8;
typedef __attribute__((ext_vector_type(8))) int int8v;
typedef __attribute__((ext_vector_type(4))) float f32x4;
typedef __attribute__((ext_vector_type(4))) unsigned short u16x4;

__device__ __forceinline__ unsigned short f2bf(float f) {
  union { float f; unsigned u; } v; v.f = f;
  return (unsigned short)((v.u + 0x7fffu + ((v.u >> 16) & 1u)) >> 16);
}

__device__ __forceinline__ void gload_lds16(const void* g, void* l) {
  __builtin_amdgcn_global_load_lds((const AS1 unsigned*)g, (AS3 unsigned*)l, 16, 0, 0);
}

#define MEMFENCE asm volatile("" ::: "memory")
#define BARRIER() do { MEMFENCE; __builtin_amdgcn_s_barrier(); MEMFENCE; } while (0)

// ---------------------------------------------------------------------------
__global__ void detect_fmt(const unsigned char* __restrict__ m, int* __restrict__ flag) {
  __shared__ int found;
  if (threadIdx.x == 0) found = 0;
  __syncthreads();
  for (int i = threadIdx.x; i < 4096; i += 256)
    if ((i & 3) != 0 && m[i] != 0) found = 1;
  __syncthreads();
  if (threadIdx.x == 0) flag[0] = found;
}

// ---------------------------------------------------------------------------
// Vectorized weight build (R2-verified).
__global__ __launch_bounds__(256) void build_w2(
    const float* __restrict__ cb, const int* __restrict__ idx,
    const unsigned char* __restrict__ fz8, const unsigned char* __restrict__ im8,
    const float* __restrict__ i8v, const float* __restrict__ wf,
    const float* __restrict__ alpha_p, const int* __restrict__ flag_p,
    unsigned short* __restrict__ w_nat, unsigned short* __restrict__ w_t,
    int R, int C) {
  __shared__ float cbs[256];
  __shared__ float tile[64][65];
  const int t = threadIdx.x;
  cbs[t] = cb[t];
  const int rBase = blockIdx.y * 64, cBase = blockIdx.x * 64;
  const float alpha = alpha_p[0];
  const int isU8 = flag_p[0];
  __syncthreads();
#pragma unroll
  for (int p = 0; p < 2; ++p) {
    const int rl = p * 32 + (t >> 3);
    const int cl = (t & 7) * 8;
    const size_t off = (size_t)(rBase + rl) * C + cBase + cl;
    float8 wv = *(const float8*)(wf + off);
    float8 qv = *(const float8*)(i8v + off);
    int8v iv = *(const int8v*)(idx + off);
    unsigned fzm[8], imm[8];
    if (isU8) {
      unsigned long long fm = *(const unsigned long long*)(fz8 + off);
      unsigned long long im = *(const unsigned long long*)(im8 + off);
#pragma unroll
      for (int k = 0; k < 8; ++k) { fzm[k] = (fm >> (8 * k)) & 255ull; imm[k] = (im >> (8 * k)) & 255ull; }
    } else {
      int8v fv = *(const int8v*)((const int*)fz8 + off);
      int8v mv = *(const int8v*)((const int*)im8 + off);
#pragma unroll
      for (int k = 0; k < 8; ++k) { fzm[k] = fv[k]; imm[k] = mv[k]; }
    }
    short8 o;
#pragma unroll
    for (int k = 0; k < 8; ++k) {
      float r = fzm[k] ? cbs[iv[k] & 255] : (imm[k] ? alpha * qv[k] : wv[k]);
      o[k] = (short)f2bf(r);
      tile[rl][cl + k] = r;
    }
    *(short8*)(w_nat + off) = o;
  }
  __syncthreads();
#pragma unroll
  for (int p = 0; p < 2; ++p) {
    const int cl = p * 32 + (t >> 3);
    const int r0 = (t & 7) * 8;
    short8 o;
#pragma unroll
    for (int j = 0; j < 8; ++j) o[j] = (short)f2bf(tile[r0 + j][cl]);
    *(short8*)(w_t + (size_t)(cBase + cl) * R + rBase + r0) = o;
  }
}

// ---------------------------------------------------------------------------
__global__ __launch_bounds__(256) void cvt_bf16(const float* __restrict__ in,
                                                unsigned short* __restrict__ out, int n4) {
  int i = blockIdx.x * 256 + threadIdx.x;
  if (i < n4) {
    float4 v = ((const float4*)in)[i];
    u16x4 r;
    r.x = f2bf(v.x); r.y = f2bf(v.y); r.z = f2bf(v.z); r.w = f2bf(v.w);
    ((u16x4*)out)[i] = r;
  }
}

// ---------------------------------------------------------------------------
// Split-K combine: out = p0 + p1 + bias; optionally also bf16 copy.
template <int WITHB16>
__global__ __launch_bounds__(256) void combine(
    const float* __restrict__ p0, const float* __restrict__ p1,
    const float* __restrict__ bias, float* __restrict__ outF,
    unsigned short* __restrict__ outB, int Nmask, int n4) {
  for (int i = blockIdx.x * 256 + threadIdx.x; i < n4; i += gridDim.x * 256) {
    float4 a = ((const float4*)p0)[i];
    float4 b = ((const float4*)p1)[i];
    float4 bv = *(const float4*)(bias + ((i * 4) & Nmask));
    float4 v;
    v.x = a.x + b.x + bv.x; v.y = a.y + b.y + bv.y;
    v.z = a.z + b.z + bv.z; v.w = a.w + b.w + bv.w;
    ((float4*)outF)[i] = v;
    if constexpr (WITHB16) {
      u16x4 r;
      r.x = f2bf(v.x); r.y = f2bf(v.y); r.z = f2bf(v.z); r.w = f2bf(v.w);
      ((u16x4*)outB)[i] = r;
    }
  }
}

// ---------------------------------------------------------------------------
// 256x256 8-phase bf16 GEMM (R2-verified schedule, unchanged). SPLIT=2 adds
// in-dispatch split-K: grid 2x tiles, id -> (tile, K-slice); adjacent swizzled
// ids share a tile (L2 locality). MODE 0: outB=bf16 c19(acc+bias);
// MODE 2: outB=bf16(acc+bias); MODE 4 (SPLIT=2): raw f32 partial to pF0/pF1.
template <int MODE, int SPLIT>
__global__ __launch_bounds__(512, 2) void gemm8(
    const unsigned short* __restrict__ A, const unsigned short* __restrict__ Bt,
    int M, int N, int K,
    const float* __restrict__ bias,
    const float* __restrict__ c_raw, const float* __restrict__ rho_raw,
    unsigned short* __restrict__ outB,
    float* __restrict__ pF0, float* __restrict__ pF1) {
  extern __shared__ unsigned short lds8[];  // 131072 B
  const int t = threadIdx.x;
  const int l = t & 63, w = t >> 6;
  const int wm = w >> 2, wn = w & 3;
  const int lr = l & 15, q = l >> 4;

  const int nwg = gridDim.x;
  const int id = (blockIdx.x & 7) * (nwg >> 3) + (blockIdx.x >> 3);
  int tileId, slice, kBase;
  if constexpr (SPLIT == 2) { tileId = id >> 1; slice = id & 1; kBase = slice * (K >> 1); }
  else { tileId = id; slice = 0; kBase = 0; }
  const int nbx = N >> 8;
  const int tileM = (tileId / nbx) * 256, tileN = (tileId % nbx) * 256;
  const int Keff = K / SPLIT;

  f32x4 acc[8][4];
#pragma unroll
  for (int mi = 0; mi < 8; ++mi)
#pragma unroll
    for (int ni = 0; ni < 4; ++ni) acc[mi][ni] = (f32x4){0.f, 0.f, 0.f, 0.f};

  const int srow = l >> 3, sslot = l & 7;
  const unsigned short* aSrc[2];
  const unsigned short* bSrc[2];
  int ldsOff[2];
#pragma unroll
  for (int i = 0; i < 2; ++i) {
    int rl = w * 16 + i * 8 + srow;
    int sl = sslot ^ (rl & 7);  // inverse swizzle on SOURCE
    aSrc[i] = A + (size_t)(tileM + rl) * K + kBase + sl * 8;
    bSrc[i] = Bt + (size_t)(tileN + rl) * K + kBase + sl * 8;
    ldsOff[i] = (w * 2 + i) * 512;
  }
  const size_t dK = (size_t)128 * K;

#define STAGE_A0(buf, kt) { gload_lds16(aSrc[0] + (kt), lds8 + (buf)*32768 + 0*8192 + ldsOff[0]); \
                            gload_lds16(aSrc[1] + (kt), lds8 + (buf)*32768 + 0*8192 + ldsOff[1]); }
#define STAGE_A1(buf, kt) { gload_lds16(aSrc[0] + dK + (kt), lds8 + (buf)*32768 + 1*8192 + ldsOff[0]); \
                            gload_lds16(aSrc[1] + dK + (kt), lds8 + (buf)*32768 + 1*8192 + ldsOff[1]); }
#define STAGE_B0(buf, kt) { gload_lds16(bSrc[0] + (kt), lds8 + (buf)*32768 + 2*8192 + ldsOff[0]); \
                            gload_lds16(bSrc[1] + (kt), lds8 + (buf)*32768 + 2*8192 + ldsOff[1]); }
#define STAGE_B1(buf, kt) { gload_lds16(bSrc[0] + dK + (kt), lds8 + (buf)*32768 + 3*8192 + ldsOff[0]); \
                            gload_lds16(bSrc[1] + dK + (kt), lds8 + (buf)*32768 + 3*8192 + ldsOff[1]); }

  const int sw = (lr & 7) << 4;
  const int k0 = (q * 16) ^ sw;
  const int k1 = (64 + q * 16) ^ sw;
  const char* ldsc = (const char*)lds8;
  const int bRowBase = (wn & 1) * 64;

  const int nt = Keff >> 6;
  STAGE_A0(0, 0); STAGE_A1(0, 0); STAGE_B0(0, 0); STAGE_B1(0, 0);
  {
    int kt1 = (nt > 1) ? 64 : 0;
    STAGE_B0(1, kt1); STAGE_B1(1, kt1);
  }
  asm volatile("s_waitcnt vmcnt(4)" ::: "memory");
  BARRIER();

  short8 af[4][2], bf[4][2];
  for (int tt = 0; tt < nt; ++tt) {
    const int cur = tt & 1, nx = cur ^ 1;
    const int ktA = (tt + 1 < nt ? tt + 1 : 0) << 6;
    const int ktB = (tt + 2 < nt ? tt + 2 : 0) << 6;
    const int aB = cur * 65536 + wm * 16384;
    const int bB = cur * 65536 + 32768 + (wn >> 1) * 16384;

    // ---- P1
#pragma unroll
    for (int mi = 0; mi < 4; ++mi) {
      af[mi][0] = *(const short8*)(ldsc + aB + (mi * 16 + lr) * 128 + k0);
      af[mi][1] = *(const short8*)(ldsc + aB + (mi * 16 + lr) * 128 + k1);
    }
#pragma unroll
    for (int ni = 0; ni < 2; ++ni) {
      bf[ni][0] = *(const short8*)(ldsc + bB + (bRowBase + ni * 16 + lr) * 128 + k0);
      bf[ni][1] = *(const short8*)(ldsc + bB + (bRowBase + ni * 16 + lr) * 128 + k1);
    }
    STAGE_A0(nx, ktA);
    BARRIER();
    asm volatile("s_waitcnt lgkmcnt(0)" ::: "memory");
    __builtin_amdgcn_s_setprio(1);
#pragma unroll
    for (int mi = 0; mi < 4; ++mi)
#pragma unroll
      for (int ni = 0; ni < 2; ++ni) {
        acc[mi][ni] = __builtin_amdgcn_mfma_f32_16x16x32_bf16(af[mi][0], bf[ni][0], acc[mi][ni], 0, 0, 0);
        acc[mi][ni] = __builtin_amdgcn_mfma_f32_16x16x32_bf16(af[mi][1], bf[ni][1], acc[mi][ni], 0, 0, 0);
      }
    __builtin_amdgcn_s_setprio(0);
    BARRIER();

    // ---- P2
#pragma unroll
    for (int ni = 2; ni < 4; ++ni) {
      bf[ni][0] = *(const short8*)(ldsc + bB + (bRowBase + ni * 16 + lr) * 128 + k0);
      bf[ni][1] = *(const short8*)(ldsc + bB + (bRowBase + ni * 16 + lr) * 128 + k1);
    }
    STAGE_A1(nx, ktA);
    BARRIER();
    asm volatile("s_waitcnt lgkmcnt(0)" ::: "memory");
    __builtin_amdgcn_s_setprio(1);
#pragma unroll
    for (int mi = 0; mi < 4; ++mi)
#pragma unroll
      for (int ni = 2; ni < 4; ++ni) {
        acc[mi][ni] = __builtin_amdgcn_mfma_f32_16x16x32_bf16(af[mi][0], bf[ni][0], acc[mi][ni], 0, 0, 0);
        acc[mi][ni] = __builtin_amdgcn_mfma_f32_16x16x32_bf16(af[mi][1], bf[ni][1], acc[mi][ni], 0, 0, 0);
      }
    __builtin_amdgcn_s_setprio(0);
    BARRIER();

    // ---- P3
#pragma unroll
    for (int mi = 0; mi < 4; ++mi) {
      af[mi][0] = *(const short8*)(ldsc + aB + ((mi + 4) * 16 + lr) * 128 + k0);
      af[mi][1] = *(const short8*)(ldsc + aB + ((mi + 4) * 16 + lr) * 128 + k1);
    }
    STAGE_B0(cur, ktB);
    BARRIER();
    asm volatile("s_waitcnt lgkmcnt(0)" ::: "memory");
    __builtin_amdgcn_s_setprio(1);
#pragma unroll
    for (int mi = 0; mi < 4; ++mi)
#pragma unroll
      for (int ni = 2; ni < 4; ++ni) {
        acc[mi + 4][ni] = __builtin_amdgcn_mfma_f32_16x16x32_bf16(af[mi][0], bf[ni][0], acc[mi + 4][ni], 0, 0, 0);
        acc[mi + 4][ni] = __builtin_amdgcn_mfma_f32_16x16x32_bf16(af[mi][1], bf[ni][1], acc[mi + 4][ni], 0, 0, 0);
      }
    __builtin_amdgcn_s_setprio(0);
    BARRIER();

    // ---- P4
    STAGE_B1(cur, ktB);
    BARRIER();
    __builtin_amdgcn_s_setprio(1);
#pragma unroll
    for (int mi = 0; mi < 4; ++mi)
#pragma unroll
      for (int ni = 0; ni < 2; ++ni) {
        acc[mi + 4][ni] = __builtin_amdgcn_mfma_f32_16x16x32_bf16(af[mi][0], bf[ni][0], acc[mi + 4][ni], 0, 0, 0);
        acc[mi + 4][ni] = __builtin_amdgcn_mfma_f32_16x16x32_bf16(af[mi][1], bf[ni][1], acc[mi + 4][ni], 0, 0, 0);
      }
    __builtin_amdgcn_s_setprio(0);
    asm volatile("s_waitcnt vmcnt(4)" ::: "memory");
    BARRIER();
  }
#undef STAGE_A0
#undef STAGE_A1
#undef STAGE_B0
#undef STAGE_B1

  // Epilogue. C/D layout: col = lr, row = q*4 + j (verified R1/R2).
  float* pOut = nullptr;
  if constexpr (MODE == 4) pOut = slice ? pF1 : pF0;
#pragma unroll
  for (int ni = 0; ni < 4; ++ni) {
    const int col = tileN + wn * 64 + ni * 16 + lr;
    float bv = 0.f, cc = 0.f, rr = 0.f, L = 0.f;
    if constexpr (MODE == 0 || MODE == 2) bv = bias[col];
    if constexpr (MODE == 0) {
      cc = fmaxf(c_raw[col], 0.1f);
      rr = fmaxf(rho_raw[col], 0.0f);
      L = 6.0f * cc;
    }
#pragma unroll
    for (int mi = 0; mi < 8; ++mi) {
      const int row0 = tileM + wm * 128 + mi * 16 + q * 4;
#pragma unroll
      for (int j = 0; j < 4; ++j) {
        float v = acc[mi][ni][j] + bv;
        size_t off = (size_t)(row0 + j) * N + col;
        if constexpr (MODE == 0) {
          float scaled = v / cc;
          float fn = floorf(scaled);
          float ttf = scaled - fn;
          float h = ttf * (1.0f - ttf);
          int ip = (int)fn;
          float sgn = (ip & 1) ? -1.0f : 1.0f;
          float interior = cc * (sgn * h + rr * h * h);
          float res = (v >= L) ? (v - L) : ((v <= -L) ? (v + L) : interior);
          outB[off] = f2bf(res);
        } else if constexpr (MODE == 2) {
          outB[off] = f2bf(v);
        } else {
          pOut[off] = v;
        }
      }
    }
  }
}

// ---------------------------------------------------------------------------
extern "C" void kernel_launch(void* const* d_in, const int* in_sizes, int n_in,
                              void* d_out, int out_size, void* d_ws, size_t ws_size,
                              hipStream_t stream) {
  (void)in_sizes; (void)n_in; (void)out_size; (void)ws_size;
  const float* x = (const float*)d_in[0];
  const float* cb1 = (const float*)d_in[1];
  const float* cb2 = (const float*)d_in[2];
  const int* idx1 = (const int*)d_in[3];
  const int* idx2 = (const int*)d_in[4];
  const unsigned char* fz1 = (const unsigned char*)d_in[5];
  const unsigned char* fz2 = (const unsigned char*)d_in[6];
  const unsigned char* im1 = (const unsigned char*)d_in[7];
  const unsigned char* im2 = (const unsigned char*)d_in[8];
  const float* i8v1 = (const float*)d_in[9];
  const float* i8v2 = (const float*)d_in[10];
  const float* wf1 = (const float*)d_in[11];
  const float* wf2 = (const float*)d_in[12];
  const float* a1 = (const float*)d_in[13];
  const float* a2 = (const float*)d_in[14];
  const float* b1 = (const float*)d_in[15];
  const float* b2 = (const float*)d_in[16];
  const float* db1 = (const float*)d_in[17];
  const float* db2 = (const float*)d_in[18];
  const float* c_raw = (const float*)d_in[19];
  const float* rho_raw = (const float*)d_in[20];

  char* ws = (char*)d_ws;
  const size_t WSZ = 33554432;  // 2048*8192*2B == 4096*2048*4B
  unsigned short* W1T = (unsigned short*)(ws + 0 * WSZ);            // [8192][2048]; partial after G1-death
  unsigned short* W1N = (unsigned short*)(ws + 1 * WSZ);            // [2048][8192]
  unsigned short* W2T = (unsigned short*)(ws + 2 * WSZ);            // [2048][8192]; partial after G2-death
  unsigned short* W2N = (unsigned short*)(ws + 3 * WSZ);            // [8192][2048]
  unsigned short* XB = (unsigned short*)(ws + 4 * WSZ);             // [4096][2048]
  unsigned short* H = (unsigned short*)(ws + 4 * WSZ + 16777216);   // [4096][8192] h, then y
  unsigned short* ZB = (unsigned short*)(ws + 4 * WSZ + 16777216 + 67108864);  // [4096][2048]
  int* flag = (int*)(ws + 4 * WSZ + 16777216 + 67108864 + 16777216);
  float* dec = (float*)d_out;
  float* zf = (float*)d_out + 8388608;

  (void)hipFuncSetAttribute((const void*)gemm8<0, 1>, hipFuncAttributeMaxDynamicSharedMemorySize, 131072);
  (void)hipFuncSetAttribute((const void*)gemm8<2, 1>, hipFuncAttributeMaxDynamicSharedMemorySize, 131072);
  (void)hipFuncSetAttribute((const void*)gemm8<4, 2>, hipFuncAttributeMaxDynamicSharedMemorySize, 131072);

  detect_fmt<<<1, 256, 0, stream>>>(fz1, flag);
  build_w2<<<dim3(8192 / 64, 2048 / 64), 256, 0, stream>>>(cb1, idx1, fz1, im1, i8v1, wf1, a1, flag, W1N, W1T, 2048, 8192);
  build_w2<<<dim3(2048 / 64, 8192 / 64), 256, 0, stream>>>(cb2, idx2, fz2, im2, i8v2, wf2, a2, flag, W2N, W2T, 8192, 2048);
  cvt_bf16<<<8192, 256, 0, stream>>>(x, XB, 2097152);

  // G1: h = c19(x @ W1 + b1)   [4096 x 8192 x K2048], 8-phase
  gemm8<0, 1><<<512, 512, 131072, stream>>>(XB, W1T, 4096, 8192, 2048, b1, c_raw, rho_raw, H, nullptr, nullptr);
  // G2: z = h @ W2 + b2        [4096 x 2048 x K8192], 8-phase split-K=2
  gemm8<4, 2><<<256, 512, 131072, stream>>>(H, W2T, 4096, 2048, 8192, nullptr, nullptr, nullptr, nullptr, zf, (float*)W1T);
  combine<1><<<2048, 256, 0, stream>>>(zf, (float*)W1T, b2, zf, ZB, 2047, 2097152);
  // G3: y = z @ W2^T + db1     [4096 x 8192 x K2048], 8-phase
  gemm8<2, 1><<<512, 512, 131072, stream>>>(ZB, W2N, 4096, 8192, 2048, db1, nullptr, nullptr, H, nullptr, nullptr);
  // G4: dec = y @ W1^T + db2   [4096 x 2048 x K8192], 8-phase split-K=2
  gemm8<4, 2><<<256, 512, 131072, stream>>>(H, W1N, 4096, 2048, 8192, nullptr, nullptr, nullptr, nullptr, dec, (float*)W2T);
  combine<0><<<2048, 256, 0, stream>>>(dec, (float*)W2T, db2, dec, nullptr, 2047, 2097152);
}

// Round 4
// 1144.423 us; speedup vs baseline: 1.2610x; 1.0336x over previous
//
#include <hip/hip_runtime.h>

#define AS1 __attribute__((address_space(1)))
#define AS3 __attribute__((address_space(3)))

typedef __attribute__((ext_vector_type(8))) short short8;
typedef __attribute__((ext_vector_type(8))) float float8;
typedef __attribute__((ext_vector_type(8))) int int8v;
typedef __attribute__((ext_vector_type(4))) float f32x4;
typedef __attribute__((ext_vector_type(4))) unsigned short u16x4;
typedef __attribute__((ext_vector_type(8))) unsigned short u16x8;

__device__ __forceinline__ unsigned short f2bf(float f) {
  union { float f; unsigned u; } v; v.f = f;
  return (unsigned short)((v.u + 0x7fffu + ((v.u >> 16) & 1u)) >> 16);
}

__device__ __forceinline__ void gload_lds16(const void* g, void* l) {
  __builtin_amdgcn_global_load_lds((const AS1 unsigned*)g, (AS3 unsigned*)l, 16, 0, 0);
}

#define MEMFENCE asm volatile("" ::: "memory")
#define BARRIER() do { MEMFENCE; __builtin_amdgcn_s_barrier(); MEMFENCE; } while (0)

// ---------------------------------------------------------------------------
__global__ void detect_fmt(const unsigned char* __restrict__ m, int* __restrict__ flag) {
  __shared__ int found;
  if (threadIdx.x == 0) found = 0;
  __syncthreads();
  for (int i = threadIdx.x; i < 4096; i += 256)
    if ((i & 3) != 0 && m[i] != 0) found = 1;
  __syncthreads();
  if (threadIdx.x == 0) flag[0] = found;
}

// ---------------------------------------------------------------------------
// Vectorized weight build (R2-verified).
__global__ __launch_bounds__(256) void build_w2(
    const float* __restrict__ cb, const int* __restrict__ idx,
    const unsigned char* __restrict__ fz8, const unsigned char* __restrict__ im8,
    const float* __restrict__ i8v, const float* __restrict__ wf,
    const float* __restrict__ alpha_p, const int* __restrict__ flag_p,
    unsigned short* __restrict__ w_nat, unsigned short* __restrict__ w_t,
    int R, int C) {
  __shared__ float cbs[256];
  __shared__ float tile[64][65];
  const int t = threadIdx.x;
  cbs[t] = cb[t];
  const int rBase = blockIdx.y * 64, cBase = blockIdx.x * 64;
  const float alpha = alpha_p[0];
  const int isU8 = flag_p[0];
  __syncthreads();
#pragma unroll
  for (int p = 0; p < 2; ++p) {
    const int rl = p * 32 + (t >> 3);
    const int cl = (t & 7) * 8;
    const size_t off = (size_t)(rBase + rl) * C + cBase + cl;
    float8 wv = *(const float8*)(wf + off);
    float8 qv = *(const float8*)(i8v + off);
    int8v iv = *(const int8v*)(idx + off);
    unsigned fzm[8], imm[8];
    if (isU8) {
      unsigned long long fm = *(const unsigned long long*)(fz8 + off);
      unsigned long long im = *(const unsigned long long*)(im8 + off);
#pragma unroll
      for (int k = 0; k < 8; ++k) { fzm[k] = (fm >> (8 * k)) & 255ull; imm[k] = (im >> (8 * k)) & 255ull; }
    } else {
      int8v fv = *(const int8v*)((const int*)fz8 + off);
      int8v mv = *(const int8v*)((const int*)im8 + off);
#pragma unroll
      for (int k = 0; k < 8; ++k) { fzm[k] = fv[k]; imm[k] = mv[k]; }
    }
    short8 o;
#pragma unroll
    for (int k = 0; k < 8; ++k) {
      float r = fzm[k] ? cbs[iv[k] & 255] : (imm[k] ? alpha * qv[k] : wv[k]);
      o[k] = (short)f2bf(r);
      tile[rl][cl + k] = r;
    }
    *(short8*)(w_nat + off) = o;
  }
  __syncthreads();
#pragma unroll
  for (int p = 0; p < 2; ++p) {
    const int cl = p * 32 + (t >> 3);
    const int r0 = (t & 7) * 8;
    short8 o;
#pragma unroll
    for (int j = 0; j < 8; ++j) o[j] = (short)f2bf(tile[r0 + j][cl]);
    *(short8*)(w_t + (size_t)(cBase + cl) * R + rBase + r0) = o;
  }
}

// ---------------------------------------------------------------------------
__global__ __launch_bounds__(256) void cvt_bf16(const float* __restrict__ in,
                                                unsigned short* __restrict__ out, int n4) {
  int i = blockIdx.x * 256 + threadIdx.x;
  if (i < n4) {
    float4 v = ((const float4*)in)[i];
    u16x4 r;
    r.x = f2bf(v.x); r.y = f2bf(v.y); r.z = f2bf(v.z); r.w = f2bf(v.w);
    ((u16x4*)out)[i] = r;
  }
}

// ---------------------------------------------------------------------------
// Split-K combine: out = p0 + p1 + bias; optionally also bf16 copy.
template <int WITHB16>
__global__ __launch_bounds__(256) void combine(
    const float* __restrict__ p0, const float* __restrict__ p1,
    const float* __restrict__ bias, float* __restrict__ outF,
    unsigned short* __restrict__ outB, int Nmask, int n4) {
  for (int i = blockIdx.x * 256 + threadIdx.x; i < n4; i += gridDim.x * 256) {
    float4 a = ((const float4*)p0)[i];
    float4 b = ((const float4*)p1)[i];
    float4 bv = *(const float4*)(bias + ((i * 4) & Nmask));
    float4 v;
    v.x = a.x + b.x + bv.x; v.y = a.y + b.y + bv.y;
    v.z = a.z + b.z + bv.z; v.w = a.w + b.w + bv.w;
    ((float4*)outF)[i] = v;
    if constexpr (WITHB16) {
      u16x4 r;
      r.x = f2bf(v.x); r.y = f2bf(v.y); r.z = f2bf(v.z); r.w = f2bf(v.w);
      ((u16x4*)outB)[i] = r;
    }
  }
}

// ---------------------------------------------------------------------------
// 256x256 8-phase bf16 GEMM (R2/R3-verified schedule, unchanged K-loop).
// R4: supertile XCD remap — XCD c owns an 8x8 tile region (SPLIT=1, grid 512)
// or a 4x4 region x 2 K-slices (SPLIT=2, grid 256; slice innermost so both
// slices of a tile co-reside on one XCD). Active per-XCD K-tile working set
// ~0.5MB << 4MB L2 -> B/A slabs L2-hit after first touch.
// R4: MODE 0/2 epilogue bounces bf16 C-tiles through (dead) LDS for full-line
// 16B/lane stores (was 32B/16-lane chunks).
template <int MODE, int SPLIT>
__global__ __launch_bounds__(512, 2) void gemm8(
    const unsigned short* __restrict__ A, const unsigned short* __restrict__ Bt,
    int M, int N, int K,
    const float* __restrict__ bias,
    const float* __restrict__ c_raw, const float* __restrict__ rho_raw,
    unsigned short* __restrict__ outB,
    float* __restrict__ pF0, float* __restrict__ pF1) {
  extern __shared__ unsigned short lds8[];  // 131072 B
  const int t = threadIdx.x;
  const int l = t & 63, w = t >> 6;
  const int wm = w >> 2, wn = w & 3;
  const int lr = l & 15, q = l >> 4;

  // Supertile XCD remap (blockIdx % 8 -> XCD round-robin heuristic).
  const int xcd = blockIdx.x & 7;
  const int local = blockIdx.x >> 3;
  int tileM, tileN, slice, kBase;
  if constexpr (SPLIT == 2) {
    slice = local & 1;
    const int tl = local >> 1;  // 0..15
    tileM = (((xcd >> 1) << 2) + (tl >> 2)) << 8;   // 4x4 region per XCD (16x8 grid)
    tileN = (((xcd & 1) << 2) + (tl & 3)) << 8;
    kBase = slice * (K >> 1);
  } else {
    slice = 0; kBase = 0;
    tileM = (((xcd >> 2) << 3) + (local >> 3)) << 8;  // 8x8 region per XCD (16x32 grid)
    tileN = (((xcd & 3) << 3) + (local & 7)) << 8;
  }
  const int Keff = K / SPLIT;

  f32x4 acc[8][4];
#pragma unroll
  for (int mi = 0; mi < 8; ++mi)
#pragma unroll
    for (int ni = 0; ni < 4; ++ni) acc[mi][ni] = (f32x4){0.f, 0.f, 0.f, 0.f};

  const int srow = l >> 3, sslot = l & 7;
  const unsigned short* aSrc[2];
  const unsigned short* bSrc[2];
  int ldsOff[2];
#pragma unroll
  for (int i = 0; i < 2; ++i) {
    int rl = w * 16 + i * 8 + srow;
    int sl = sslot ^ (rl & 7);  // inverse swizzle on SOURCE
    aSrc[i] = A + (size_t)(tileM + rl) * K + kBase + sl * 8;
    bSrc[i] = Bt + (size_t)(tileN + rl) * K + kBase + sl * 8;
    ldsOff[i] = (w * 2 + i) * 512;
  }
  const size_t dK = (size_t)128 * K;

#define STAGE_A0(buf, kt) { gload_lds16(aSrc[0] + (kt), lds8 + (buf)*32768 + 0*8192 + ldsOff[0]); \
                            gload_lds16(aSrc[1] + (kt), lds8 + (buf)*32768 + 0*8192 + ldsOff[1]); }
#define STAGE_A1(buf, kt) { gload_lds16(aSrc[0] + dK + (kt), lds8 + (buf)*32768 + 1*8192 + ldsOff[0]); \
                            gload_lds16(aSrc[1] + dK + (kt), lds8 + (buf)*32768 + 1*8192 + ldsOff[1]); }
#define STAGE_B0(buf, kt) { gload_lds16(bSrc[0] + (kt), lds8 + (buf)*32768 + 2*8192 + ldsOff[0]); \
                            gload_lds16(bSrc[1] + (kt), lds8 + (buf)*32768 + 2*8192 + ldsOff[1]); }
#define STAGE_B1(buf, kt) { gload_lds16(bSrc[0] + dK + (kt), lds8 + (buf)*32768 + 3*8192 + ldsOff[0]); \
                            gload_lds16(bSrc[1] + dK + (kt), lds8 + (buf)*32768 + 3*8192 + ldsOff[1]); }

  const int sw = (lr & 7) << 4;
  const int k0 = (q * 16) ^ sw;
  const int k1 = (64 + q * 16) ^ sw;
  const char* ldsc = (const char*)lds8;
  const int bRowBase = (wn & 1) * 64;

  const int nt = Keff >> 6;
  STAGE_A0(0, 0); STAGE_A1(0, 0); STAGE_B0(0, 0); STAGE_B1(0, 0);
  {
    int kt1 = (nt > 1) ? 64 : 0;
    STAGE_B0(1, kt1); STAGE_B1(1, kt1);
  }
  asm volatile("s_waitcnt vmcnt(4)" ::: "memory");
  BARRIER();

  short8 af[4][2], bf[4][2];
  for (int tt = 0; tt < nt; ++tt) {
    const int cur = tt & 1, nx = cur ^ 1;
    const int ktA = (tt + 1 < nt ? tt + 1 : 0) << 6;
    const int ktB = (tt + 2 < nt ? tt + 2 : 0) << 6;
    const int aB = cur * 65536 + wm * 16384;
    const int bB = cur * 65536 + 32768 + (wn >> 1) * 16384;

    // ---- P1
#pragma unroll
    for (int mi = 0; mi < 4; ++mi) {
      af[mi][0] = *(const short8*)(ldsc + aB + (mi * 16 + lr) * 128 + k0);
      af[mi][1] = *(const short8*)(ldsc + aB + (mi * 16 + lr) * 128 + k1);
    }
#pragma unroll
    for (int ni = 0; ni < 2; ++ni) {
      bf[ni][0] = *(const short8*)(ldsc + bB + (bRowBase + ni * 16 + lr) * 128 + k0);
      bf[ni][1] = *(const short8*)(ldsc + bB + (bRowBase + ni * 16 + lr) * 128 + k1);
    }
    STAGE_A0(nx, ktA);
    BARRIER();
    asm volatile("s_waitcnt lgkmcnt(0)" ::: "memory");
    __builtin_amdgcn_s_setprio(1);
#pragma unroll
    for (int mi = 0; mi < 4; ++mi)
#pragma unroll
      for (int ni = 0; ni < 2; ++ni) {
        acc[mi][ni] = __builtin_amdgcn_mfma_f32_16x16x32_bf16(af[mi][0], bf[ni][0], acc[mi][ni], 0, 0, 0);
        acc[mi][ni] = __builtin_amdgcn_mfma_f32_16x16x32_bf16(af[mi][1], bf[ni][1], acc[mi][ni], 0, 0, 0);
      }
    __builtin_amdgcn_s_setprio(0);
    BARRIER();

    // ---- P2
#pragma unroll
    for (int ni = 2; ni < 4; ++ni) {
      bf[ni][0] = *(const short8*)(ldsc + bB + (bRowBase + ni * 16 + lr) * 128 + k0);
      bf[ni][1] = *(const short8*)(ldsc + bB + (bRowBase + ni * 16 + lr) * 128 + k1);
    }
    STAGE_A1(nx, ktA);
    BARRIER();
    asm volatile("s_waitcnt lgkmcnt(0)" ::: "memory");
    __builtin_amdgcn_s_setprio(1);
#pragma unroll
    for (int mi = 0; mi < 4; ++mi)
#pragma unroll
      for (int ni = 2; ni < 4; ++ni) {
        acc[mi][ni] = __builtin_amdgcn_mfma_f32_16x16x32_bf16(af[mi][0], bf[ni][0], acc[mi][ni], 0, 0, 0);
        acc[mi][ni] = __builtin_amdgcn_mfma_f32_16x16x32_bf16(af[mi][1], bf[ni][1], acc[mi][ni], 0, 0, 0);
      }
    __builtin_amdgcn_s_setprio(0);
    BARRIER();

    // ---- P3
#pragma unroll
    for (int mi = 0; mi < 4; ++mi) {
      af[mi][0] = *(const short8*)(ldsc + aB + ((mi + 4) * 16 + lr) * 128 + k0);
      af[mi][1] = *(const short8*)(ldsc + aB + ((mi + 4) * 16 + lr) * 128 + k1);
    }
    STAGE_B0(cur, ktB);
    BARRIER();
    asm volatile("s_waitcnt lgkmcnt(0)" ::: "memory");
    __builtin_amdgcn_s_setprio(1);
#pragma unroll
    for (int mi = 0; mi < 4; ++mi)
#pragma unroll
      for (int ni = 2; ni < 4; ++ni) {
        acc[mi + 4][ni] = __builtin_amdgcn_mfma_f32_16x16x32_bf16(af[mi][0], bf[ni][0], acc[mi + 4][ni], 0, 0, 0);
        acc[mi + 4][ni] = __builtin_amdgcn_mfma_f32_16x16x32_bf16(af[mi][1], bf[ni][1], acc[mi + 4][ni], 0, 0, 0);
      }
    __builtin_amdgcn_s_setprio(0);
    BARRIER();

    // ---- P4
    STAGE_B1(cur, ktB);
    BARRIER();
    __builtin_amdgcn_s_setprio(1);
#pragma unroll
    for (int mi = 0; mi < 4; ++mi)
#pragma unroll
      for (int ni = 0; ni < 2; ++ni) {
        acc[mi + 4][ni] = __builtin_amdgcn_mfma_f32_16x16x32_bf16(af[mi][0], bf[ni][0], acc[mi + 4][ni], 0, 0, 0);
        acc[mi + 4][ni] = __builtin_amdgcn_mfma_f32_16x16x32_bf16(af[mi][1], bf[ni][1], acc[mi + 4][ni], 0, 0, 0);
      }
    __builtin_amdgcn_s_setprio(0);
    asm volatile("s_waitcnt vmcnt(4)" ::: "memory");
    BARRIER();
  }
#undef STAGE_A0
#undef STAGE_A1
#undef STAGE_B0
#undef STAGE_B1

  // Epilogue. C/D layout: col = lr, row = q*4 + j (verified R1/R2).
  if constexpr (MODE == 0 || MODE == 2) {
    // Per-ni column params (col independent of mi).
    float bv4[4], cc4[4], rr4[4], L4[4];
#pragma unroll
    for (int ni = 0; ni < 4; ++ni) {
      const int col = tileN + wn * 64 + ni * 16 + lr;
      bv4[ni] = bias[col];
      if constexpr (MODE == 0) {
        cc4[ni] = fmaxf(c_raw[col], 0.1f);
        rr4[ni] = fmaxf(rho_raw[col], 0.0f);
        L4[ni] = 6.0f * cc4[ni];
      }
    }
    // LDS is dead after draining in-flight stages.
    asm volatile("s_waitcnt vmcnt(0)" ::: "memory");
    BARRIER();
    unsigned short* sc = lds8 + w * 1152;  // wave-private 16 x 72 u16 (padded)
#pragma unroll
    for (int mi = 0; mi < 8; ++mi) {
#pragma unroll
      for (int ni = 0; ni < 4; ++ni)
#pragma unroll
        for (int j = 0; j < 4; ++j) {
          float v = acc[mi][ni][j] + bv4[ni];
          float res;
          if constexpr (MODE == 0) {
            float scaled = v / cc4[ni];
            float fn = floorf(scaled);
            float ttf = scaled - fn;
            float h = ttf * (1.0f - ttf);
            int ip = (int)fn;
            float sgn = (ip & 1) ? -1.0f : 1.0f;
            float interior = cc4[ni] * (sgn * h + rr4[ni] * h * h);
            res = (v >= L4[ni]) ? (v - L4[ni]) : ((v <= -L4[ni]) ? (v + L4[ni]) : interior);
          } else {
            res = v;
          }
          sc[(q * 4 + j) * 72 + ni * 16 + lr] = f2bf(res);
        }
      asm volatile("s_waitcnt lgkmcnt(0)" ::: "memory");
#pragma unroll
      for (int sgi = 0; sgi < 2; ++sgi) {
        const int s = sgi * 64 + l;
        const int r = s >> 3, cs = (s & 7) * 8;
        u16x8 vv = *(const u16x8*)(sc + r * 72 + cs);
        const int row = tileM + wm * 128 + mi * 16 + r;
        const int col = tileN + wn * 64 + cs;
        *(u16x8*)(outB + (size_t)row * N + col) = vv;
      }
      asm volatile("s_waitcnt lgkmcnt(0)" ::: "memory");
    }
  } else {  // MODE 4: f32 partials, 16-lane x 4B = full 64B segments already.
    float* pOut = slice ? pF1 : pF0;
#pragma unroll
    for (int ni = 0; ni < 4; ++ni) {
      const int col = tileN + wn * 64 + ni * 16 + lr;
#pragma unroll
      for (int mi = 0; mi < 8; ++mi) {
        const int row0 = tileM + wm * 128 + mi * 16 + q * 4;
#pragma unroll
        for (int j = 0; j < 4; ++j)
          pOut[(size_t)(row0 + j) * N + col] = acc[mi][ni][j];
      }
    }
  }
}

// ---------------------------------------------------------------------------
extern "C" void kernel_launch(void* const* d_in, const int* in_sizes, int n_in,
                              void* d_out, int out_size, void* d_ws, size_t ws_size,
                              hipStream_t stream) {
  (void)in_sizes; (void)n_in; (void)out_size; (void)ws_size;
  const float* x = (const float*)d_in[0];
  const float* cb1 = (const float*)d_in[1];
  const float* cb2 = (const float*)d_in[2];
  const int* idx1 = (const int*)d_in[3];
  const int* idx2 = (const int*)d_in[4];
  const unsigned char* fz1 = (const unsigned char*)d_in[5];
  const unsigned char* fz2 = (const unsigned char*)d_in[6];
  const unsigned char* im1 = (const unsigned char*)d_in[7];
  const unsigned char* im2 = (const unsigned char*)d_in[8];
  const float* i8v1 = (const float*)d_in[9];
  const float* i8v2 = (const float*)d_in[10];
  const float* wf1 = (const float*)d_in[11];
  const float* wf2 = (const float*)d_in[12];
  const float* a1 = (const float*)d_in[13];
  const float* a2 = (const float*)d_in[14];
  const float* b1 = (const float*)d_in[15];
  const float* b2 = (const float*)d_in[16];
  const float* db1 = (const float*)d_in[17];
  const float* db2 = (const float*)d_in[18];
  const float* c_raw = (const float*)d_in[19];
  const float* rho_raw = (const float*)d_in[20];

  char* ws = (char*)d_ws;
  const size_t WSZ = 33554432;  // 2048*8192*2B == 4096*2048*4B
  unsigned short* W1T = (unsigned short*)(ws + 0 * WSZ);            // [8192][2048]; partial after G1-death
  unsigned short* W1N = (unsigned short*)(ws + 1 * WSZ);            // [2048][8192]
  unsigned short* W2T = (unsigned short*)(ws + 2 * WSZ);            // [2048][8192]; partial after G2-death
  unsigned short* W2N = (unsigned short*)(ws + 3 * WSZ);            // [8192][2048]
  unsigned short* XB = (unsigned short*)(ws + 4 * WSZ);             // [4096][2048]
  unsigned short* H = (unsigned short*)(ws + 4 * WSZ + 16777216);   // [4096][8192] h, then y
  unsigned short* ZB = (unsigned short*)(ws + 4 * WSZ + 16777216 + 67108864);  // [4096][2048]
  int* flag = (int*)(ws + 4 * WSZ + 16777216 + 67108864 + 16777216);
  float* dec = (float*)d_out;
  float* zf = (float*)d_out + 8388608;

  (void)hipFuncSetAttribute((const void*)gemm8<0, 1>, hipFuncAttributeMaxDynamicSharedMemorySize, 131072);
  (void)hipFuncSetAttribute((const void*)gemm8<2, 1>, hipFuncAttributeMaxDynamicSharedMemorySize, 131072);
  (void)hipFuncSetAttribute((const void*)gemm8<4, 2>, hipFuncAttributeMaxDynamicSharedMemorySize, 131072);

  detect_fmt<<<1, 256, 0, stream>>>(fz1, flag);
  build_w2<<<dim3(8192 / 64, 2048 / 64), 256, 0, stream>>>(cb1, idx1, fz1, im1, i8v1, wf1, a1, flag, W1N, W1T, 2048, 8192);
  build_w2<<<dim3(2048 / 64, 8192 / 64), 256, 0, stream>>>(cb2, idx2, fz2, im2, i8v2, wf2, a2, flag, W2N, W2T, 8192, 2048);
  cvt_bf16<<<8192, 256, 0, stream>>>(x, XB, 2097152);

  // G1: h = c19(x @ W1 + b1)   [4096 x 8192 x K2048], 8-phase supertiled
  gemm8<0, 1><<<512, 512, 131072, stream>>>(XB, W1T, 4096, 8192, 2048, b1, c_raw, rho_raw, H, nullptr, nullptr);
  // G2: z = h @ W2 + b2        [4096 x 2048 x K8192], 8-phase split-K=2
  gemm8<4, 2><<<256, 512, 131072, stream>>>(H, W2T, 4096, 2048, 8192, nullptr, nullptr, nullptr, nullptr, zf, (float*)W1T);
  combine<1><<<2048, 256, 0, stream>>>(zf, (float*)W1T, b2, zf, ZB, 2047, 2097152);
  // G3: y = z @ W2^T + db1     [4096 x 8192 x K2048], 8-phase supertiled
  gemm8<2, 1><<<512, 512, 131072, stream>>>(ZB, W2N, 4096, 8192, 2048, db1, nullptr, nullptr, H, nullptr, nullptr);
  // G4: dec = y @ W1^T + db2   [4096 x 2048 x K8192], 8-phase split-K=2
  gemm8<4, 2><<<256, 512, 131072, stream>>>(H, W1N, 4096, 2048, 8192, nullptr, nullptr, nullptr, nullptr, dec, (float*)W2T);
  combine<0><<<2048, 256, 0, stream>>>(dec, (float*)W2T, db2, dec, nullptr, 2047, 2097152);
}